// Round 1
// baseline (320.751 us; speedup 1.0000x reference)
//
#include <hip/hip_runtime.h>
#include <math.h>

#define N_V 12288
#define D_F 32
#define N_E 196608
#define KNN 6
#define EPSF 1e-12f

#define SEGS 32
#define JSEG (N_V / SEGS)      // 384
#define TILE_J 128
#define RPT 4                  // rows per thread
#define K1_BLOCK 128
#define ROWS_PER_BLOCK (K1_BLOCK * RPT)     // 512
#define ROW_BLOCKS (N_V / ROWS_PER_BLOCK)   // 24

static_assert(N_V % SEGS == 0, "");
static_assert(JSEG % TILE_J == 0, "");
static_assert(N_V % ROWS_PER_BLOCK == 0, "");
static_assert(N_E % 256 == 0, "");

// ---------- kernel 0: sq[i] = ||x_i||^2 (4-partial order, shared with dot) ----------
__global__ void sq_kernel(const float* __restrict__ x, float* __restrict__ sq) {
    int i = blockIdx.x * blockDim.x + threadIdx.x;
    if (i >= N_V) return;
    const float4* xr = (const float4*)(x + i * D_F);
    float a0 = 0.f, a1 = 0.f, a2 = 0.f, a3 = 0.f;
#pragma unroll
    for (int d = 0; d < 8; ++d) {
        float4 p = xr[d];
        a0 += p.x * p.x; a1 += p.y * p.y; a2 += p.z * p.z; a3 += p.w * p.w;
    }
    sq[i] = (a0 + a1) + (a2 + a3);
}

// ---------- kernel 1: per-(row, j-segment) top-6 smallest d2 ----------
__global__ __launch_bounds__(K1_BLOCK) void topk_partial(
    const float* __restrict__ x, const float* __restrict__ sq,
    float* __restrict__ cand) {
    __shared__ float xs[TILE_J * D_F];
    __shared__ float sqs[TILE_J];

    const int t = threadIdx.x;
    const int rowBase = blockIdx.x * ROWS_PER_BLOCK;
    const int seg = blockIdx.y;
    const int j0 = seg * JSEG;

    float xi[RPT][D_F];
    float sqi[RPT];
    float tk[RPT][KNN];   // sorted ascending d2
#pragma unroll
    for (int m = 0; m < RPT; ++m) {
        const int r = rowBase + t + m * K1_BLOCK;
        const float4* xr = (const float4*)(x + r * D_F);
#pragma unroll
        for (int d = 0; d < 8; ++d) {
            float4 p = xr[d];
            xi[m][4 * d + 0] = p.x; xi[m][4 * d + 1] = p.y;
            xi[m][4 * d + 2] = p.z; xi[m][4 * d + 3] = p.w;
        }
        sqi[m] = sq[r];
#pragma unroll
        for (int k = 0; k < KNN; ++k) tk[m][k] = 3.0e38f;
    }

    for (int tile = 0; tile < JSEG; tile += TILE_J) {
        __syncthreads();
        // stage TILE_J rows (contiguous 16 KB) + their sq
        {
            const float4* src = (const float4*)(x + (size_t)(j0 + tile) * D_F);
            float4* dst = (float4*)xs;
#pragma unroll
            for (int u = t; u < TILE_J * D_F / 4; u += K1_BLOCK) dst[u] = src[u];
            if (t < TILE_J / 4)
                ((float4*)sqs)[t] = ((const float4*)(sq + j0 + tile))[t];
        }
        __syncthreads();

        for (int jj = 0; jj < TILE_J; ++jj) {
            const float sqj = sqs[jj];
            float acc[RPT][4];
#pragma unroll
            for (int m = 0; m < RPT; ++m)
                acc[m][0] = acc[m][1] = acc[m][2] = acc[m][3] = 0.f;
#pragma unroll
            for (int d = 0; d < 8; ++d) {
                float4 b = ((const float4*)(xs + jj * D_F))[d];   // broadcast read
#pragma unroll
                for (int m = 0; m < RPT; ++m) {
                    acc[m][0] += xi[m][4 * d + 0] * b.x;
                    acc[m][1] += xi[m][4 * d + 1] * b.y;
                    acc[m][2] += xi[m][4 * d + 2] * b.z;
                    acc[m][3] += xi[m][4 * d + 3] * b.w;
                }
            }
#pragma unroll
            for (int m = 0; m < RPT; ++m) {
                const float dot = (acc[m][0] + acc[m][1]) + (acc[m][2] + acc[m][3]);
                const float d2 = sqi[m] + sqj - 2.0f * dot;
                // branchless sorted insert into ascending tk[m][0..5]
                const float nv = d2;
                float y0 = fminf(tk[m][0], nv);
                float y1 = fminf(tk[m][1], fmaxf(tk[m][0], nv));
                float y2 = fminf(tk[m][2], fmaxf(tk[m][1], nv));
                float y3 = fminf(tk[m][3], fmaxf(tk[m][2], nv));
                float y4 = fminf(tk[m][4], fmaxf(tk[m][3], nv));
                float y5 = fminf(tk[m][5], fmaxf(tk[m][4], nv));
                tk[m][0] = y0; tk[m][1] = y1; tk[m][2] = y2;
                tk[m][3] = y3; tk[m][4] = y4; tk[m][5] = y5;
            }
        }
    }

#pragma unroll
    for (int m = 0; m < RPT; ++m) {
        const int r = rowBase + t + m * K1_BLOCK;
        float* c = cand + ((size_t)r * SEGS + seg) * KNN;
#pragma unroll
        for (int k = 0; k < KNN; ++k) c[k] = tk[m][k];
    }
}

// ---------- kernel 2: merge per-segment top-6 -> v, write vertex rows ----------
__global__ void merge_v(const float* __restrict__ cand, float* __restrict__ v,
                        float* __restrict__ out) {
    int i = blockIdx.x * blockDim.x + threadIdx.x;
    if (i >= N_V) return;
    float tk[KNN];
#pragma unroll
    for (int k = 0; k < KNN; ++k) tk[k] = 3.0e38f;
    const float* c = cand + (size_t)i * SEGS * KNN;
    for (int s = 0; s < SEGS * KNN; ++s) {
        const float nv = c[s];
        float y0 = fminf(tk[0], nv);
        float y1 = fminf(tk[1], fmaxf(tk[0], nv));
        float y2 = fminf(tk[2], fmaxf(tk[1], nv));
        float y3 = fminf(tk[3], fmaxf(tk[2], nv));
        float y4 = fminf(tk[4], fmaxf(tk[3], nv));
        float y5 = fminf(tk[5], fmaxf(tk[4], nv));
        tk[0] = y0; tk[1] = y1; tk[2] = y2; tk[3] = y3; tk[4] = y4; tk[5] = y5;
    }
    float s = 0.f;
#pragma unroll
    for (int k = 1; k < KNN; ++k)
        s += expf(-sqrtf(fmaxf(tk[k], EPSF)));
    const float vi = 1.0f - s / (float)KNN;
    v[i] = vi;
    out[2 * i] = vi;
    out[2 * i + 1] = 0.0f;
}

// ---------- kernel 3: edge filtration ----------
__global__ void edge_kernel(const float* __restrict__ x, const int* __restrict__ ei,
                            const float* __restrict__ v, float* __restrict__ out) {
    int e = blockIdx.x * blockDim.x + threadIdx.x;
    if (e >= N_E) return;
    const int u = ei[e];
    const int w = ei[N_E + e];
    const float4* xu = (const float4*)(x + (size_t)u * D_F);
    const float4* xw = (const float4*)(x + (size_t)w * D_F);
    float a0 = 0.f, a1 = 0.f, a2 = 0.f, a3 = 0.f;
#pragma unroll
    for (int d = 0; d < 8; ++d) {
        float4 p = xu[d], q = xw[d];
        float dx = p.x - q.x, dy = p.y - q.y, dz = p.z - q.z, dw = p.w - q.w;
        a0 += dx * dx; a1 += dy * dy; a2 += dz * dz; a3 += dw * dw;
    }
    const float enorm = sqrtf(fmaxf((a0 + a1) + (a2 + a3), EPSF));
    const float ey = 1.0f - expf(-enorm);
    const float ev = fmaxf(v[u], v[w]);
    out[2 * (N_V + e) + 0] = ev;
    out[2 * (N_V + e) + 1] = ey;
}

extern "C" void kernel_launch(void* const* d_in, const int* in_sizes, int n_in,
                              void* d_out, int out_size, void* d_ws, size_t ws_size,
                              hipStream_t stream) {
    const float* x = (const float*)d_in[0];
    const int* ei = (const int*)d_in[1];
    float* out = (float*)d_out;
    float* ws = (float*)d_ws;

    float* sq = ws;                       // N_V floats
    float* v = ws + N_V;                  // N_V floats
    float* cand = ws + 2 * N_V;           // N_V * SEGS * KNN floats (~9.4 MB)

    sq_kernel<<<N_V / 256, 256, 0, stream>>>(x, sq);

    dim3 g1(ROW_BLOCKS, SEGS);
    topk_partial<<<g1, K1_BLOCK, 0, stream>>>(x, sq, cand);

    merge_v<<<N_V / 256, 256, 0, stream>>>(cand, v, out);

    edge_kernel<<<N_E / 256, 256, 0, stream>>>(x, ei, v, out);
}

// Round 2
// 149.900 us; speedup vs baseline: 2.1398x; 2.1398x over previous
//
#include <hip/hip_runtime.h>
#include <math.h>

#define N_V 12288
#define D_F 32
#define N_E 196608
#define KNN 6
#define EPSF 1e-12f

#define SEGS 8
#define JSEG (N_V / SEGS)          // 1536 columns per segment
#define SUBTILES (JSEG / 16)       // 96 MFMA column subtiles per segment
#define ROWS_PER_BLOCK 128         // 4 waves x 32 rows
#define ROW_BLOCKS (N_V / ROWS_PER_BLOCK)  // 96

typedef __bf16 bf16x8 __attribute__((ext_vector_type(8)));
typedef float f32x4 __attribute__((ext_vector_type(4)));

static_assert(N_V % ROWS_PER_BLOCK == 0, "");
static_assert(JSEG % 16 == 0, "");

__device__ __forceinline__ unsigned short f2bf(float f) {
    unsigned u = __builtin_bit_cast(unsigned, f);
    unsigned r = u + 0x7fffu + ((u >> 16) & 1u);   // round-to-nearest-even
    return (unsigned short)(r >> 16);
}

// ---------- kernel 0: bf16 convert + sq ----------
__global__ __launch_bounds__(256) void prep_kernel(const float* __restrict__ x,
                                                   unsigned short* __restrict__ xb,
                                                   float* __restrict__ sq) {
    int i = blockIdx.x * 256 + threadIdx.x;
    if (i >= N_V) return;
    const float4* xr = (const float4*)(x + (size_t)i * D_F);
    float a0 = 0.f, a1 = 0.f, a2 = 0.f, a3 = 0.f;
    unsigned short h[D_F];
#pragma unroll
    for (int d = 0; d < 8; ++d) {
        float4 p = xr[d];
        a0 += p.x * p.x; a1 += p.y * p.y; a2 += p.z * p.z; a3 += p.w * p.w;
        h[4 * d + 0] = f2bf(p.x); h[4 * d + 1] = f2bf(p.y);
        h[4 * d + 2] = f2bf(p.z); h[4 * d + 3] = f2bf(p.w);
    }
    sq[i] = (a0 + a1) + (a2 + a3);
    unsigned pk[16];
#pragma unroll
    for (int j = 0; j < 16; ++j)
        pk[j] = (unsigned)h[2 * j] | ((unsigned)h[2 * j + 1] << 16);
    uint4* dst = (uint4*)(xb + (size_t)i * D_F);
#pragma unroll
    for (int j = 0; j < 4; ++j)
        dst[j] = make_uint4(pk[4 * j], pk[4 * j + 1], pk[4 * j + 2], pk[4 * j + 3]);
}

// ---------- kernel 1: MFMA gram + per-row top-6 keys ----------
// key = dot(x_i,x_j) - 0.5*sq_j ; per row, 6 LARGEST keys == 6 smallest d2.
__global__ __launch_bounds__(256, 3) void topk_mfma(
    const unsigned short* __restrict__ xb, const float* __restrict__ sq,
    float* __restrict__ cand) {
    __shared__ float lmerge[4 * 32 * 97];   // [wave][row][16 lists x 6, pad 97]

    const int t = threadIdx.x;
    const int wave = t >> 6;
    const int lane = t & 63;
    const int quad = lane >> 4;
    const int l16 = lane & 15;

    const int rowbase = blockIdx.x * ROWS_PER_BLOCK + wave * 32;
    const int seg = blockIdx.y;
    const int j0 = seg * JSEG;

    // A fragments: A[m=lane&15][k=quad*8+j], rows register-resident for life of block
    bf16x8 afrag[2];
#pragma unroll
    for (int rt = 0; rt < 2; ++rt)
        afrag[rt] = *reinterpret_cast<const bf16x8*>(
            xb + (size_t)(rowbase + rt * 16 + l16) * D_F + quad * 8);

    float tk[8][KNN];   // [rt*4+reg][k], sorted descending keys
#pragma unroll
    for (int s = 0; s < 8; ++s)
#pragma unroll
        for (int k = 0; k < KNN; ++k) tk[s][k] = -3.0e38f;

#pragma unroll 2
    for (int it = 0; it < SUBTILES; ++it) {
        const int col0 = j0 + it * 16;
        const bf16x8 bfrag = *reinterpret_cast<const bf16x8*>(
            xb + (size_t)(col0 + l16) * D_F + quad * 8);
        const float sqj = sq[col0 + l16];
#pragma unroll
        for (int rt = 0; rt < 2; ++rt) {
            f32x4 c = {0.f, 0.f, 0.f, 0.f};
            c = __builtin_amdgcn_mfma_f32_16x16x32_bf16(afrag[rt], bfrag, c, 0, 0, 0);
#pragma unroll
            for (int reg = 0; reg < 4; ++reg) {
                const float nv = fmaf(-0.5f, sqj, c[reg]);
                float* s = tk[rt * 4 + reg];
                float y0 = fmaxf(s[0], nv);
                float y1 = fmaxf(s[1], fminf(s[0], nv));
                float y2 = fmaxf(s[2], fminf(s[1], nv));
                float y3 = fmaxf(s[3], fminf(s[2], nv));
                float y4 = fmaxf(s[4], fminf(s[3], nv));
                float y5 = fmaxf(s[5], fminf(s[4], nv));
                s[0] = y0; s[1] = y1; s[2] = y2; s[3] = y3; s[4] = y4; s[5] = y5;
            }
        }
    }

    // ---- cross-lane merge: 16 lanes hold each row's column subsets ----
#pragma unroll
    for (int s = 0; s < 8; ++s) {
        const int row = (s >> 2) * 16 + quad * 4 + (s & 3);
        float* dst = lmerge + wave * (32 * 97) + row * 97 + l16 * 6;
#pragma unroll
        for (int k = 0; k < KNN; ++k) dst[k] = tk[s][k];
    }
    __syncthreads();

    {
        const int row = lane >> 1;      // 2 lanes per row
        const int half = lane & 1;
        const float* srcl = lmerge + wave * (32 * 97) + row * 97 + half * 48;
        float mk[KNN];
#pragma unroll
        for (int k = 0; k < KNN; ++k) mk[k] = -3.0e38f;
        for (int j = 0; j < 48; ++j) {
            const float nv = srcl[j];
            float y0 = fmaxf(mk[0], nv);
            float y1 = fmaxf(mk[1], fminf(mk[0], nv));
            float y2 = fmaxf(mk[2], fminf(mk[1], nv));
            float y3 = fmaxf(mk[3], fminf(mk[2], nv));
            float y4 = fmaxf(mk[4], fminf(mk[3], nv));
            float y5 = fmaxf(mk[5], fminf(mk[4], nv));
            mk[0] = y0; mk[1] = y1; mk[2] = y2; mk[3] = y3; mk[4] = y4; mk[5] = y5;
        }
        const int g = rowbase + row;
        float* dst = cand + ((size_t)g * SEGS + seg) * 12 + half * 6;
#pragma unroll
        for (int k = 0; k < KNN; ++k) dst[k] = mk[k];
    }
}

// ---------- kernel 2: merge per-segment keys -> v, vertex rows ----------
__global__ __launch_bounds__(256) void merge_v(const float* __restrict__ cand,
                                               const float* __restrict__ sq,
                                               float* __restrict__ v,
                                               float* __restrict__ out) {
    int i = blockIdx.x * 256 + threadIdx.x;
    if (i >= N_V) return;
    float tk[KNN];
#pragma unroll
    for (int k = 0; k < KNN; ++k) tk[k] = -3.0e38f;
    const float4* c = (const float4*)(cand + (size_t)i * (SEGS * 12));
    for (int s4 = 0; s4 < SEGS * 12 / 4; ++s4) {
        float4 q = c[s4];
        float vals[4] = {q.x, q.y, q.z, q.w};
#pragma unroll
        for (int u = 0; u < 4; ++u) {
            const float nv = vals[u];
            float y0 = fmaxf(tk[0], nv);
            float y1 = fmaxf(tk[1], fminf(tk[0], nv));
            float y2 = fmaxf(tk[2], fminf(tk[1], nv));
            float y3 = fmaxf(tk[3], fminf(tk[2], nv));
            float y4 = fmaxf(tk[4], fminf(tk[3], nv));
            float y5 = fmaxf(tk[5], fminf(tk[4], nv));
            tk[0] = y0; tk[1] = y1; tk[2] = y2; tk[3] = y3; tk[4] = y4; tk[5] = y5;
        }
    }
    // tk descending keys -> d2 ascending; index 0 is self, drop it
    const float sqi = sq[i];
    float ssum = 0.f;
#pragma unroll
    for (int m = 1; m < KNN; ++m) {
        const float d2 = fmaf(-2.0f, tk[m], sqi);
        ssum += expf(-sqrtf(fmaxf(d2, EPSF)));
    }
    const float vi = 1.0f - ssum / (float)KNN;
    v[i] = vi;
    out[2 * i] = vi;
    out[2 * i + 1] = 0.0f;
}

// ---------- kernel 3: edge filtration ----------
__global__ __launch_bounds__(256) void edge_kernel(const float* __restrict__ x,
                                                   const int* __restrict__ ei,
                                                   const float* __restrict__ v,
                                                   float* __restrict__ out) {
    int e = blockIdx.x * 256 + threadIdx.x;
    if (e >= N_E) return;
    const int u = ei[e];
    const int w = ei[N_E + e];
    const float4* xu = (const float4*)(x + (size_t)u * D_F);
    const float4* xw = (const float4*)(x + (size_t)w * D_F);
    float a0 = 0.f, a1 = 0.f, a2 = 0.f, a3 = 0.f;
#pragma unroll
    for (int d = 0; d < 8; ++d) {
        float4 p = xu[d], q = xw[d];
        float dx = p.x - q.x, dy = p.y - q.y, dz = p.z - q.z, dw = p.w - q.w;
        a0 += dx * dx; a1 += dy * dy; a2 += dz * dz; a3 += dw * dw;
    }
    const float enorm = sqrtf(fmaxf((a0 + a1) + (a2 + a3), EPSF));
    const float ey = 1.0f - expf(-enorm);
    const float ev = fmaxf(v[u], v[w]);
    out[2 * (N_V + e) + 0] = ev;
    out[2 * (N_V + e) + 1] = ey;
}

extern "C" void kernel_launch(void* const* d_in, const int* in_sizes, int n_in,
                              void* d_out, int out_size, void* d_ws, size_t ws_size,
                              hipStream_t stream) {
    const float* x = (const float*)d_in[0];
    const int* ei = (const int*)d_in[1];
    float* out = (float*)d_out;
    char* ws = (char*)d_ws;

    unsigned short* xb = (unsigned short*)ws;                 // 786432 B
    float* sq = (float*)(ws + 786432);                        // 49152 B
    float* v  = (float*)(ws + 786432 + 49152);                // 49152 B
    float* cand = (float*)(ws + 786432 + 2 * 49152);          // 4718592 B

    prep_kernel<<<(N_V + 255) / 256, 256, 0, stream>>>(x, xb, sq);

    dim3 g1(ROW_BLOCKS, SEGS);
    topk_mfma<<<g1, 256, 0, stream>>>(xb, sq, cand);

    merge_v<<<(N_V + 255) / 256, 256, 0, stream>>>(cand, sq, v, out);

    edge_kernel<<<N_E / 256, 256, 0, stream>>>(x, ei, v, out);
}

// Round 3
// 118.089 us; speedup vs baseline: 2.7162x; 1.2694x over previous
//
#include <hip/hip_runtime.h>
#include <math.h>

#define N_V 12288
#define D_F 32
#define N_E 196608
#define KNN 6
#define EPSF 1e-12f

#define SEGS 16
#define JSEG (N_V / SEGS)          // 768 query rows? no: columns per segment
#define SUBTILES (JSEG / 16)       // 48 j-subtiles per segment
#define ROWS_PER_BLOCK 128         // 4 waves x 32 query rows
#define ROW_BLOCKS (N_V / ROWS_PER_BLOCK)  // 96  -> grid 96 x 16 = 1536 blocks

typedef __bf16 bf16x8 __attribute__((ext_vector_type(8)));
typedef float f32x4 __attribute__((ext_vector_type(4)));

static_assert(N_V % ROWS_PER_BLOCK == 0, "");
static_assert(JSEG % 16 == 0, "");

__device__ __forceinline__ unsigned short f2bf(float f) {
    unsigned u = __builtin_bit_cast(unsigned, f);
    unsigned r = u + 0x7fffu + ((u >> 16) & 1u);   // RNE
    return (unsigned short)(r >> 16);
}

// descending sorted 6-list insert: 1 max + 5 med3
__device__ __forceinline__ void ins6(float s[KNN], float nv) {
    float y0 = fmaxf(s[0], nv);
    float y1 = __builtin_amdgcn_fmed3f(s[0], s[1], nv);
    float y2 = __builtin_amdgcn_fmed3f(s[1], s[2], nv);
    float y3 = __builtin_amdgcn_fmed3f(s[2], s[3], nv);
    float y4 = __builtin_amdgcn_fmed3f(s[3], s[4], nv);
    float y5 = __builtin_amdgcn_fmed3f(s[4], s[5], nv);
    s[0] = y0; s[1] = y1; s[2] = y2; s[3] = y3; s[4] = y4; s[5] = y5;
}

// ---------- kernel 0: bf16 convert + sq + msq(-0.5*sq) ----------
__global__ __launch_bounds__(256) void prep_kernel(const float* __restrict__ x,
                                                   unsigned short* __restrict__ xb,
                                                   float* __restrict__ sq,
                                                   float* __restrict__ msq) {
    int i = blockIdx.x * 256 + threadIdx.x;
    if (i >= N_V) return;
    const float4* xr = (const float4*)(x + (size_t)i * D_F);
    float a0 = 0.f, a1 = 0.f, a2 = 0.f, a3 = 0.f;
    unsigned short h[D_F];
#pragma unroll
    for (int d = 0; d < 8; ++d) {
        float4 p = xr[d];
        a0 += p.x * p.x; a1 += p.y * p.y; a2 += p.z * p.z; a3 += p.w * p.w;
        h[4 * d + 0] = f2bf(p.x); h[4 * d + 1] = f2bf(p.y);
        h[4 * d + 2] = f2bf(p.z); h[4 * d + 3] = f2bf(p.w);
    }
    const float s = (a0 + a1) + (a2 + a3);
    sq[i] = s;
    msq[i] = -0.5f * s;
    unsigned pk[16];
#pragma unroll
    for (int j = 0; j < 16; ++j)
        pk[j] = (unsigned)h[2 * j] | ((unsigned)h[2 * j + 1] << 16);
    uint4* dst = (uint4*)(xb + (size_t)i * D_F);
#pragma unroll
    for (int j = 0; j < 4; ++j)
        dst[j] = make_uint4(pk[4 * j], pk[4 * j + 1], pk[4 * j + 2], pk[4 * j + 3]);
}

// ---------- kernel 1: MFMA gram + per-row top-6 keys, no LDS ----------
// A = candidate rows (j), B = query rows (i). C[m=quad*4+reg][n=l16]:
// lane's query row = i0 + l16 (+16 per rt), candidates j = col0+quad*4+reg.
// acc init = msq[j] => C = dot - 0.5*sq_j directly (the selection key).
__global__ __launch_bounds__(256, 6) void topk_mfma(
    const unsigned short* __restrict__ xb, const float* __restrict__ msq,
    float* __restrict__ cand) {
    const int t = threadIdx.x;
    const int wave = t >> 6;
    const int lane = t & 63;
    const int quad = lane >> 4;
    const int l16 = lane & 15;

    const int rowbase = blockIdx.x * ROWS_PER_BLOCK + wave * 32;
    const int seg = blockIdx.y;
    const int j0 = seg * JSEG;

    // B fragments: query rows, register-resident
    bf16x8 bfrag[2];
#pragma unroll
    for (int rt = 0; rt < 2; ++rt)
        bfrag[rt] = *reinterpret_cast<const bf16x8*>(
            xb + (size_t)(rowbase + rt * 16 + l16) * D_F + quad * 8);

    float tk[2][KNN];
#pragma unroll
    for (int rt = 0; rt < 2; ++rt)
#pragma unroll
        for (int k = 0; k < KNN; ++k) tk[rt][k] = -3.0e38f;

    const unsigned short* aptr = xb + (size_t)(j0 + l16) * D_F + quad * 8;
    const float* mptr = msq + j0 + quad * 4;

    bf16x8 afrag = *reinterpret_cast<const bf16x8*>(aptr);
    float4 m4 = *reinterpret_cast<const float4*>(mptr);

    for (int it = 0; it < SUBTILES; ++it) {
        const int nxt = (it + 1 < SUBTILES) ? (it + 1) : it;   // clamped prefetch
        bf16x8 anext = *reinterpret_cast<const bf16x8*>(aptr + (size_t)nxt * 16 * D_F);
        float4 mnext = *reinterpret_cast<const float4*>(mptr + nxt * 16);

        f32x4 cinit = {m4.x, m4.y, m4.z, m4.w};
#pragma unroll
        for (int rt = 0; rt < 2; ++rt) {
            f32x4 c = __builtin_amdgcn_mfma_f32_16x16x32_bf16(afrag, bfrag[rt], cinit, 0, 0, 0);
#pragma unroll
            for (int reg = 0; reg < 4; ++reg)
                ins6(tk[rt], c[reg]);
        }
        afrag = anext;
        m4 = mnext;
    }

    // ---- cross-quad merge via shuffles (row's lists live in 4 quads, same l16) ----
#pragma unroll
    for (int rt = 0; rt < 2; ++rt) {
#pragma unroll
        for (int rnd = 0; rnd < 2; ++rnd) {
            const int mask = 16 << rnd;
            float b[KNN];
#pragma unroll
            for (int k = 0; k < KNN; ++k) b[k] = __shfl_xor(tk[rt][k], mask, 64);
#pragma unroll
            for (int k = 0; k < KNN; ++k) ins6(tk[rt], b[k]);
        }
    }

    if (quad == 0) {
#pragma unroll
        for (int rt = 0; rt < 2; ++rt) {
            const int g = rowbase + rt * 16 + l16;
            float* dst = cand + ((size_t)g * SEGS + seg) * KNN;
#pragma unroll
            for (int k = 0; k < KNN; ++k) dst[k] = tk[rt][k];
        }
    }
}

// ---------- kernel 2: merge per-segment keys -> v ----------
__global__ __launch_bounds__(256) void merge_v(const float* __restrict__ cand,
                                               const float* __restrict__ sq,
                                               float* __restrict__ v,
                                               float* __restrict__ out) {
    int i = blockIdx.x * 256 + threadIdx.x;
    if (i >= N_V) return;
    float tk[KNN];
#pragma unroll
    for (int k = 0; k < KNN; ++k) tk[k] = -3.0e38f;
    const float4* c = (const float4*)(cand + (size_t)i * (SEGS * KNN));
    for (int s4 = 0; s4 < SEGS * KNN / 4; ++s4) {
        float4 q = c[s4];
        ins6(tk, q.x); ins6(tk, q.y); ins6(tk, q.z); ins6(tk, q.w);
    }
    // tk: descending keys == ascending d2; rank 0 is self, drop it
    const float sqi = sq[i];
    float ssum = 0.f;
#pragma unroll
    for (int m = 1; m < KNN; ++m) {
        const float d2 = fmaf(-2.0f, tk[m], sqi);
        ssum += expf(-sqrtf(fmaxf(d2, EPSF)));
    }
    const float vi = 1.0f - ssum / (float)KNN;
    v[i] = vi;
    out[2 * i] = vi;
    out[2 * i + 1] = 0.0f;
}

// ---------- kernel 3: edge filtration ----------
__global__ __launch_bounds__(256) void edge_kernel(const float* __restrict__ x,
                                                   const int* __restrict__ ei,
                                                   const float* __restrict__ v,
                                                   float* __restrict__ out) {
    int e = blockIdx.x * 256 + threadIdx.x;
    if (e >= N_E) return;
    const int u = ei[e];
    const int w = ei[N_E + e];
    const float4* xu = (const float4*)(x + (size_t)u * D_F);
    const float4* xw = (const float4*)(x + (size_t)w * D_F);
    float a0 = 0.f, a1 = 0.f, a2 = 0.f, a3 = 0.f;
#pragma unroll
    for (int d = 0; d < 8; ++d) {
        float4 p = xu[d], q = xw[d];
        float dx = p.x - q.x, dy = p.y - q.y, dz = p.z - q.z, dw = p.w - q.w;
        a0 += dx * dx; a1 += dy * dy; a2 += dz * dz; a3 += dw * dw;
    }
    const float enorm = sqrtf(fmaxf((a0 + a1) + (a2 + a3), EPSF));
    const float ey = 1.0f - expf(-enorm);
    const float ev = fmaxf(v[u], v[w]);
    out[2 * (N_V + e) + 0] = ev;
    out[2 * (N_V + e) + 1] = ey;
}

extern "C" void kernel_launch(void* const* d_in, const int* in_sizes, int n_in,
                              void* d_out, int out_size, void* d_ws, size_t ws_size,
                              hipStream_t stream) {
    const float* x = (const float*)d_in[0];
    const int* ei = (const int*)d_in[1];
    float* out = (float*)d_out;
    char* ws = (char*)d_ws;

    unsigned short* xb = (unsigned short*)ws;                  // 786432 B
    float* sq  = (float*)(ws + 786432);                        // 49152 B
    float* msq = (float*)(ws + 786432 + 49152);                // 49152 B
    float* v   = (float*)(ws + 786432 + 2 * 49152);            // 49152 B
    float* cand = (float*)(ws + 786432 + 3 * 49152);           // 4718592 B (~5.6 MB total)

    prep_kernel<<<(N_V + 255) / 256, 256, 0, stream>>>(x, xb, sq, msq);

    dim3 g1(ROW_BLOCKS, SEGS);
    topk_mfma<<<g1, 256, 0, stream>>>(xb, msq, cand);

    merge_v<<<(N_V + 255) / 256, 256, 0, stream>>>(cand, sq, v, out);

    edge_kernel<<<N_E / 256, 256, 0, stream>>>(x, ei, v, out);
}